// Round 1
// baseline (90.748 us; speedup 1.0000x reference)
//
#include <hip/hip_runtime.h>

#define GDIM 76
#define GG (GDIM * GDIM)
#define DDIM 85
#define ADIM 3
#define LDSW (GDIM + 1)   // 77: stride mod 32 = 13, coprime with 32 -> conflict-free

// One block handles one (b, a, i) slab-row: 85 channels x 76 columns.
__global__ __launch_bounds__(256) void yolo_kernel(const float* __restrict__ x,
                                                   float* __restrict__ out) {
    const int blk  = blockIdx.x;
    const int i    = blk % GDIM;        // grid row (g1)
    const int slab = blk / GDIM;        // b*A + a
    const int a    = slab % ADIM;

    __shared__ float lds[DDIM * LDSW];  // 85*77*4 = 26180 B

    // ---- load phase: coalesced reads along g2 ----
    const float* __restrict__ src = x + (size_t)slab * (DDIM * GG) + (size_t)i * GDIM;
    for (int idx = threadIdx.x; idx < DDIM * GDIM; idx += 256) {
        const int d = idx / GDIM;
        const int g = idx - d * GDIM;
        lds[d * LDSW + g] = src[(size_t)d * GG + g];
    }
    __syncthreads();

    // anchors (ANCHORS / STRIDE * STRIDE = ANCHORS)
    const float aw = (a == 0) ? 10.0f : (a == 1) ? 16.0f : 33.0f;
    const float ah = (a == 0) ? 13.0f : (a == 1) ? 30.0f : 23.0f;
    const float fi = (float)i;

    // ---- store phase: coalesced writes along (g2, d) ----
    float* __restrict__ dst = out + (size_t)slab * ((size_t)GG * DDIM)
                                  + (size_t)i * GDIM * DDIM;
    for (int idx = threadIdx.x; idx < DDIM * GDIM; idx += 256) {
        const int g = idx / DDIM;       // g2 (column j)
        const int d = idx - g * DDIM;
        const float v = lds[d * LDSW + g];
        float r;
        if (d == 3) {
            r = __expf(v) * aw;
        } else if (d == 4) {
            r = __expf(v) * ah;
        } else {
            const float s = 1.0f / (1.0f + __expf(-v));
            if (d == 1)      r = (s + fi) * 8.0f;
            else if (d == 2) r = (s + (float)g) * 8.0f;
            else             r = s;
        }
        dst[idx] = r;
    }
}

extern "C" void kernel_launch(void* const* d_in, const int* in_sizes, int n_in,
                              void* d_out, int out_size, void* d_ws, size_t ws_size,
                              hipStream_t stream) {
    const float* x = (const float*)d_in[0];
    float* out = (float*)d_out;
    const int B = in_sizes[0] / (ADIM * DDIM * GG);   // 32
    const int nblocks = B * ADIM * GDIM;              // 7296
    yolo_kernel<<<dim3(nblocks), dim3(256), 0, stream>>>(x, out);
}

// Round 2
// 84.114 us; speedup vs baseline: 1.0789x; 1.0789x over previous
//
#include <hip/hip_runtime.h>

#define GDIM 76
#define GG (GDIM * GDIM)          // 5776
#define DDIM 85
#define ADIM 3
#define LDSW 77                   // stride mod 32 = 13; store-phase lane step 4*77 ≡ 20 (mod 32) -> 8 distinct banks
#define NV4 ((DDIM * GDIM) / 4)   // 1615 float4 per tile
#define ROWV4 (GDIM / 4)          // 19 float4 per input row

// One block per (b, a, i) slab-row: 85 channels x 76 columns, transposed via LDS.
__global__ __launch_bounds__(256) void yolo_kernel(const float* __restrict__ x,
                                                   float* __restrict__ out) {
    const int blk  = blockIdx.x;
    const int i    = blk % GDIM;
    const int slab = blk / GDIM;  // b*A + a
    const int a    = slab % ADIM;

    __shared__ float lds[DDIM * LDSW];   // 26180 B -> 6 blocks/CU

    // ---- load phase: float4 coalesced reads, scalar LDS writes ----
    const float* __restrict__ src = x + (size_t)slab * (DDIM * GG) + i * GDIM;
    #pragma unroll
    for (int t = 0; t < 7; ++t) {
        const int idx = threadIdx.x + t * 256;
        if (idx < NV4) {
            const int d = idx / ROWV4;           // magic-mul div by 19
            const int k = idx - d * ROWV4;
            const float4 v = *(const float4*)(src + (size_t)d * GG + k * 4);
            float* p = &lds[d * LDSW + k * 4];
            p[0] = v.x; p[1] = v.y; p[2] = v.z; p[3] = v.w;
        }
    }
    __syncthreads();

    const float aw = (a == 0) ? 10.0f : (a == 1) ? 16.0f : 33.0f;
    const float ah = (a == 0) ? 13.0f : (a == 1) ? 30.0f : 23.0f;
    const float fi = (float)i;

    // ---- store phase: scalar LDS reads, float4 coalesced writes ----
    float* __restrict__ dst = out + (size_t)slab * ((size_t)GG * DDIM)
                                  + (size_t)i * (GDIM * DDIM);
    #pragma unroll
    for (int t = 0; t < 7; ++t) {
        const int idx = threadIdx.x + t * 256;
        if (idx < NV4) {
            const int fbase = idx * 4;
            const int g0 = fbase / DDIM;         // magic-mul div by 85
            const int d0 = fbase - g0 * DDIM;
            float r[4];
            #pragma unroll
            for (int e = 0; e < 4; ++e) {
                int d  = d0 + e;
                int ge = g0;
                if (d >= DDIM) { d -= DDIM; ge += 1; }   // cndmask pair
                const float v = lds[d * LDSW + ge];
                const bool iswh = (d == 3) | (d == 4);
                const float ev = __expf(iswh ? v : -v);  // one exp per element
                const float s  = __builtin_amdgcn_rcpf(1.0f + ev);
                float rr = s;
                if (d == 1)  rr = (s + fi) * 8.0f;
                if (d == 2)  rr = (s + (float)ge) * 8.0f;
                if (iswh)    rr = ev * ((d == 3) ? aw : ah);
                r[e] = rr;
            }
            *(float4*)(dst + fbase) = make_float4(r[0], r[1], r[2], r[3]);
        }
    }
}

extern "C" void kernel_launch(void* const* d_in, const int* in_sizes, int n_in,
                              void* d_out, int out_size, void* d_ws, size_t ws_size,
                              hipStream_t stream) {
    const float* x = (const float*)d_in[0];
    float* out = (float*)d_out;
    const int B = in_sizes[0] / (ADIM * DDIM * GG);   // 32
    const int nblocks = B * ADIM * GDIM;              // 7296
    yolo_kernel<<<dim3(nblocks), dim3(256), 0, stream>>>(x, out);
}

// Round 3
// 80.935 us; speedup vs baseline: 1.1212x; 1.0393x over previous
//
#include <hip/hip_runtime.h>

#define GDIM 76
#define GG (GDIM * GDIM)          // 5776
#define DDIM 85
#define ADIM 3
#define LDSW 77                   // lane stride 77 ≡ 13 (mod 32), coprime -> conflict-free scalar access
#define NELEM (DDIM * GDIM)       // 6460
#define NV4 (NELEM / 4)           // 1615 = 19 * 85  (the key factorization)
#define ROWV4 (GDIM / 4)          // 19

// One block per (b, a, i) slab-row: 85 channels x 76 columns, transposed via LDS.
// Activation is applied in the LOAD phase (d uniform per float4); the store
// phase is a pure conflict-free LDS->global coalesced copy.
__global__ __launch_bounds__(256) void yolo_kernel(const float* __restrict__ x,
                                                   float* __restrict__ out) {
    const int blk  = blockIdx.x;
    const int i    = blk % GDIM;
    const int slab = blk / GDIM;  // b*A + a
    const int a    = slab % ADIM;

    __shared__ float lds[DDIM * LDSW];   // 26180 B -> 6 blocks/CU

    const float aw  = (a == 0) ? 10.0f : (a == 1) ? 16.0f : 33.0f;
    const float ah  = (a == 0) ? 13.0f : (a == 1) ? 30.0f : 23.0f;
    const float fi8 = (float)i * 8.0f;   // d==1: (s+i)*8 = 8s + 8i

    // ---- load phase: float4 coalesced reads + activation + contiguous LDS writes ----
    const float* __restrict__ src = x + (size_t)slab * (DDIM * GG) + i * GDIM;
    for (int idx = threadIdx.x; idx < NV4; idx += 256) {
        const int d = idx / ROWV4;           // magic-mul div by 19 (uniform per float4)
        const int k = idx - d * ROWV4;
        const float4 v = *(const float4*)(src + (size_t)d * GG + 4 * k);

        const bool iswh = (d == 3) | (d == 4);
        const bool isx  = (d == 1);
        const bool isy  = (d == 2);
        const float A   = (d == 3) ? aw : ah;
        const float C   = (isx | isy) ? 8.0f : 1.0f;
        const float Bc  = isx ? fi8 : 0.0f;
        const float gk8 = (float)(4 * k) * 8.0f;

        float r[4];
        const float vv[4] = {v.x, v.y, v.z, v.w};
        #pragma unroll
        for (int e = 0; e < 4; ++e) {
            const float val = vv[e];
            const float ev  = __expf(iswh ? val : -val);       // one exp per element
            const float s   = __builtin_amdgcn_rcpf(1.0f + ev);
            const float B   = isy ? (gk8 + (float)(8 * e)) : Bc;
            const float rs  = s * C + B;                        // fma
            r[e] = iswh ? ev * A : rs;
        }
        float* p = &lds[d * LDSW + 4 * k];
        p[0] = r[0]; p[1] = r[1]; p[2] = r[2]; p[3] = r[3];
    }
    __syncthreads();

    // ---- store phase: pure copy. flat = t + e*1615; since 1615 = 19*85,
    // d = t%85 is e-invariant and g = t/85 + 19e. Lane stride in LDS = 77
    // floats == 13 mod 32 -> conflict-free; global stores lane-contiguous. ----
    float* __restrict__ dst = out + (size_t)slab * ((size_t)GG * DDIM)
                                  + (size_t)i * (GDIM * DDIM);
    for (int t = threadIdx.x; t < NV4; t += 256) {
        const int g0 = t / DDIM;             // magic-mul div by 85 (once per thread)
        const int d  = t - g0 * DDIM;
        const int base = d * LDSW + g0;
        #pragma unroll
        for (int e = 0; e < 4; ++e) {
            dst[t + e * NV4] = lds[base + e * ROWV4];   // ds_read imm offsets 0/76/152/228 B
        }
    }
}

extern "C" void kernel_launch(void* const* d_in, const int* in_sizes, int n_in,
                              void* d_out, int out_size, void* d_ws, size_t ws_size,
                              hipStream_t stream) {
    const float* x = (const float*)d_in[0];
    float* out = (float*)d_out;
    const int B = in_sizes[0] / (ADIM * DDIM * GG);   // 32
    const int nblocks = B * ADIM * GDIM;              // 7296
    yolo_kernel<<<dim3(nblocks), dim3(256), 0, stream>>>(x, out);
}